// Round 4
// baseline (259.200 us; speedup 1.0000x reference)
//
#include <hip/hip_runtime.h>
#include <hip/hip_bf16.h>

typedef _Float16 f16x8 __attribute__((ext_vector_type(8)));
typedef float f32x4 __attribute__((ext_vector_type(4)));
typedef unsigned int u32;
typedef u32 u32x2 __attribute__((ext_vector_type(2)));

#define LOG2E 1.4426950408889634f

// B=16, C=512, HEAD=8, D=64, N=1024 (W=H=32)

__device__ inline void gll16(const void* g, void* l) {
  __builtin_amdgcn_global_load_lds(
      (const __attribute__((address_space(1))) void*)g,
      (__attribute__((address_space(3))) void*)l, 16, 0, 0);
}

// ---------------- prep: Wall f16 + pos f16 (pos pre-scaled by log2e) ----------------
__global__ __launch_bounds__(256) void prep_kernel(
    const float* __restrict__ Wq, const float* __restrict__ Wk, const float* __restrict__ Wv,
    const float* __restrict__ rel_h, const float* __restrict__ rel_w,
    _Float16* __restrict__ Wall, _Float16* __restrict__ post) {
  int idx = blockIdx.x * 256 + threadIdx.x;
  if (idx < 1536 * 512) {
    int o = idx >> 9;
    float wv;
    if (o < 512) wv = Wq[idx];
    else if (o < 1024) wv = Wk[idx - 512 * 512];
    else wv = Wv[idx - 1024 * 512];
    Wall[idx] = (_Float16)wv;
  } else {
    int p = idx - 1536 * 512;            // [0, 8*1024*64)
    int h = p >> 16;
    int rem = p & 65535;
    int n = rem >> 6;
    int d = rem & 63;
    float v = rel_h[(h * 64 + d) * 32 + (n & 31)] + rel_w[(h * 64 + d) * 32 + (n >> 5)];
    post[p] = (_Float16)(v * LOG2E);
  }
}

// ---------------- transpose: x[B,C,N] f32 -> Xt[B*N, C] f16 ----------------
__global__ __launch_bounds__(256) void transpose_kernel(
    const float* __restrict__ x, _Float16* __restrict__ Xt) {
  __shared__ float tl[64][65];
  int bid = blockIdx.x;
  int b = bid >> 7;
  int rem = bid & 127;
  int c0 = (rem >> 4) * 64;
  int n0 = (rem & 15) * 64;
  int t = threadIdx.x;
#pragma unroll
  for (int p = 0; p < 16; ++p) {
    int idx = p * 256 + t;
    int i = idx >> 6, j = idx & 63;
    tl[i][j] = x[((size_t)b * 512 + c0 + i) * 1024 + n0 + j];
  }
  __syncthreads();
#pragma unroll
  for (int p = 0; p < 16; ++p) {
    int idx = p * 256 + t;
    int j = idx >> 6, i = idx & 63;
    Xt[((size_t)b * 1024 + n0 + j) * 512 + c0 + i] = (_Float16)tl[i][j];
  }
}

// ---------------- QKV projection GEMM ----------------
// writes Kext[b][h][n][0:64]=k*log2e, [64:128]=q ; v[b][h][d][n]  (f16)
__global__ __launch_bounds__(256) void qkv_gemm(
    const _Float16* __restrict__ Wall, const _Float16* __restrict__ Xt,
    const float* __restrict__ bq, const float* __restrict__ bk, const float* __restrict__ bv,
    _Float16* __restrict__ kext, _Float16* __restrict__ vv) {
  __shared__ _Float16 At[128 * 64];
  __shared__ _Float16 Bt[128 * 64];
  int bid = blockIdx.x;
  int mb = bid >> 7, nb = bid & 127;
  int o0 = mb * 128, j0 = nb * 128;
  int t = threadIdx.x;
  int w = t >> 6, l = t & 63, lg = l >> 4, lc = l & 15;
  int wm = w >> 1, wn = w & 1;
  f32x4 acc[4][4];
#pragma unroll
  for (int a = 0; a < 4; ++a)
#pragma unroll
    for (int bb = 0; bb < 4; ++bb) acc[a][bb] = (f32x4){0.f, 0.f, 0.f, 0.f};

  for (int k0 = 0; k0 < 512; k0 += 64) {
    __syncthreads();
#pragma unroll
    for (int p = 0; p < 4; ++p) {
      int li = p * 256 + t;            // 16B chunk index
      int row = li >> 3;               // tile row
      int colb = (li & 7) << 4;        // linear byte col in row
      int scol = (colb ^ ((row & 7) << 4)) >> 1;  // inverse-swizzled f16 col
      gll16(Wall + (size_t)(o0 + row) * 512 + k0 + scol, At + (size_t)li * 8);
      gll16(Xt + (size_t)(j0 + row) * 512 + k0 + scol, Bt + (size_t)li * 8);
    }
    __syncthreads();
#pragma unroll
    for (int kf = 0; kf < 2; ++kf) {
      int kbyte = kf * 64 + lg * 16;
      f16x8 af[4], bf[4];
#pragma unroll
      for (int mi = 0; mi < 4; ++mi) {
        int row = wm * 64 + mi * 16 + lc;
        af[mi] = *(const f16x8*)((const char*)At + row * 128 + (kbyte ^ ((row & 7) << 4)));
      }
#pragma unroll
      for (int ni = 0; ni < 4; ++ni) {
        int row = wn * 64 + ni * 16 + lc;
        bf[ni] = *(const f16x8*)((const char*)Bt + row * 128 + (kbyte ^ ((row & 7) << 4)));
      }
#pragma unroll
      for (int mi = 0; mi < 4; ++mi)
#pragma unroll
        for (int ni = 0; ni < 4; ++ni)
          acc[mi][ni] = __builtin_amdgcn_mfma_f32_16x16x32_f16(af[mi], bf[ni], acc[mi][ni], 0, 0, 0);
    }
  }

  int mode = mb >> 2;  // 0=q, 1=k, 2=v
  const float* bias = (mode == 0) ? bq : ((mode == 1) ? bk : bv);
#pragma unroll
  for (int mi = 0; mi < 4; ++mi) {
    int obase = o0 + wm * 64 + mi * 16 + 4 * lg - mode * 512;
#pragma unroll
    for (int ni = 0; ni < 4; ++ni) {
      int j = j0 + wn * 64 + ni * 16 + lc;
      int b = j >> 10, n = j & 1023;
#pragma unroll
      for (int r = 0; r < 4; ++r) {
        int op = obase + r;                 // channel within matrix [0,512)
        float y = acc[mi][ni][r] + bias[op];
        if (mode == 1) y *= LOG2E;          // fold exp2 base change into k
        int h = op >> 6, d = op & 63;
        if (mode < 2) {
          size_t off = ((((size_t)b * 8 + h) * 1024 + n) * 128) + d + (mode == 0 ? 64 : 0);
          kext[off] = (_Float16)y;
        } else {
          vv[(((size_t)b * 8 + h) * 64 + d) * 1024 + n] = (_Float16)y;
        }
      }
    }
  }
}

// ---------------- fused flash attention + residual ----------------
// Barrier-free: 1 wave per block, 32 q-rows; K/V direct from global (L2).
// Swapped-operand: S = mfma(K_frag, A_frag) -> lane owns q-col = lc.
__global__ __launch_bounds__(64, 3) void attn_kernel(
    const _Float16* __restrict__ kext, const _Float16* __restrict__ vv,
    const _Float16* __restrict__ post,
    const float* __restrict__ x, float* __restrict__ out) {
  __shared__ char Pl[32 * 80];   // P bounce: 32 q-rows x 32 m f16, padded to 80B rows
  int bid = blockIdx.x;
  int xcd = bid & 7, rest = bid >> 3;
  int bh = ((rest >> 5) << 3) | xcd;   // sweep bh sequentially per XCD
  int qb = rest & 31;
  int b = bh >> 3, h = bh & 7;
  int l = threadIdx.x, lg = l >> 4, lc = l & 15;
  const _Float16* keg = kext + (size_t)bh * (1024 * 128);
  const _Float16* vbh = vv + (size_t)bh * 65536;
  const _Float16* ph = post + (size_t)h * 65536;
  int n0w = qb * 32;

  // A-ext frags (q | pos*log2e), kept in regs all kernel
  f16x8 aq[2][4];
#pragma unroll
  for (int rf = 0; rf < 2; ++rf)
#pragma unroll
    for (int kf = 0; kf < 4; ++kf) {
      int kk = kf * 32 + lg * 8;
      int n = n0w + rf * 16 + lc;
      const _Float16* src = (kf < 2) ? (keg + (size_t)n * 128 + 64 + kk)
                                     : (ph + (size_t)n * 64 + (kk - 64));
      aq[rf][kf] = *(const f16x8*)src;
    }

  float m_r[2], l_r[2];
  f32x4 oacc[2][4];
#pragma unroll
  for (int rf = 0; rf < 2; ++rf) {
    m_r[rf] = -1e30f; l_r[rf] = 0.f;
#pragma unroll
    for (int dt = 0; dt < 4; ++dt) oacc[rf][dt] = (f32x4){0.f, 0.f, 0.f, 0.f};
  }

  for (int mt = 0; mt < 32; ++mt) {
    int m0 = mt << 5;
    // K-frags (m-rows = lc within 16-block; k = kf*32 + 8lg + j)
    f16x8 bkf[2][4];
#pragma unroll
    for (int ms = 0; ms < 2; ++ms)
#pragma unroll
      for (int kf = 0; kf < 4; ++kf)
        bkf[ms][kf] = *(const f16x8*)(keg + (size_t)(m0 + ms * 16 + lc) * 128 + kf * 32 + 8 * lg);
    // V-frags (d-rows = dt*16+lc; k = m-local = 8lg + j)
    f16x8 bvv[4];
#pragma unroll
    for (int dt = 0; dt < 4; ++dt)
      bvv[dt] = *(const f16x8*)(vbh + (size_t)(dt * 16 + lc) * 1024 + m0 + 8 * lg);

    // QK^T-ext swapped: sS[rf][ms] = C[m-local = 4lg+r, q = lc]
    f32x4 sS[2][2];
#pragma unroll
    for (int rf = 0; rf < 2; ++rf)
#pragma unroll
      for (int ms = 0; ms < 2; ++ms) sS[rf][ms] = (f32x4){0.f, 0.f, 0.f, 0.f};
    __builtin_amdgcn_s_setprio(1);
#pragma unroll
    for (int ms = 0; ms < 2; ++ms)
#pragma unroll
      for (int rf = 0; rf < 2; ++rf)
#pragma unroll
        for (int kf = 0; kf < 4; ++kf)
          sS[rf][ms] = __builtin_amdgcn_mfma_f32_16x16x32_f16(bkf[ms][kf], aq[rf][kf], sS[rf][ms], 0, 0, 0);
    __builtin_amdgcn_s_setprio(0);

    // online softmax (log2 domain); lane owns q = lc, 8 m-values per rf
#pragma unroll
    for (int rf = 0; rf < 2; ++rf) {
      float mx = sS[rf][0][0];
#pragma unroll
      for (int ms = 0; ms < 2; ++ms)
#pragma unroll
        for (int r = 0; r < 4; ++r) mx = fmaxf(mx, sS[rf][ms][r]);
      mx = fmaxf(mx, __shfl_xor(mx, 16));
      mx = fmaxf(mx, __shfl_xor(mx, 32));
      float mnew = fmaxf(m_r[rf], mx);
      float scl = exp2f(m_r[rf] - mnew);
      m_r[rf] = mnew;
      float rsum = 0.f;
      char* pb = Pl + (rf * 16 + lc) * 80;
#pragma unroll
      for (int ms = 0; ms < 2; ++ms) {
        float p0 = exp2f(sS[rf][ms][0] - mnew);
        float p1 = exp2f(sS[rf][ms][1] - mnew);
        float p2 = exp2f(sS[rf][ms][2] - mnew);
        float p3 = exp2f(sS[rf][ms][3] - mnew);
        rsum += (p0 + p1) + (p2 + p3);
        u32 lo = __builtin_bit_cast(u32, __builtin_amdgcn_cvt_pkrtz(p0, p1));
        u32 hi = __builtin_bit_cast(u32, __builtin_amdgcn_cvt_pkrtz(p2, p3));
        *(u32x2*)(pb + ms * 32 + 8 * lg) = (u32x2){lo, hi};
      }
      rsum += __shfl_xor(rsum, 16);
      rsum += __shfl_xor(rsum, 32);
      l_r[rf] = l_r[rf] * scl + rsum;
#pragma unroll
      for (int dt = 0; dt < 4; ++dt)
#pragma unroll
        for (int r = 0; r < 4; ++r) oacc[rf][dt][r] *= scl;
    }

    // PV swapped: oacc = mfma(V_frag, P_frag) -> C[d = 4lg+r, q = lc]
    __builtin_amdgcn_s_setprio(1);
#pragma unroll
    for (int rf = 0; rf < 2; ++rf) {
      f16x8 pa = *(const f16x8*)(Pl + (rf * 16 + lc) * 80 + 16 * lg);
#pragma unroll
      for (int dt = 0; dt < 4; ++dt)
        oacc[rf][dt] = __builtin_amdgcn_mfma_f32_16x16x32_f16(bvv[dt], pa, oacc[rf][dt], 0, 0, 0);
    }
    __builtin_amdgcn_s_setprio(0);
    // same-wave LDS ordering: no barrier needed (1 wave per block)
  }

  // epilogue: lane holds d = dt*16+4lg+r, q = n0w+rf*16+lc
#pragma unroll
  for (int rf = 0; rf < 2; ++rf) {
    float inv = 1.0f / l_r[rf];
    int n = n0w + rf * 16 + lc;
#pragma unroll
    for (int dt = 0; dt < 4; ++dt)
#pragma unroll
      for (int r = 0; r < 4; ++r) {
        int c = h * 64 + dt * 16 + 4 * lg + r;
        size_t off = ((size_t)b * 512 + c) * 1024 + n;
        out[off] = oacc[rf][dt][r] * inv + x[off];
      }
  }
}

extern "C" void kernel_launch(void* const* d_in, const int* in_sizes, int n_in,
                              void* d_out, int out_size, void* d_ws, size_t ws_size,
                              hipStream_t stream) {
  (void)in_sizes; (void)n_in; (void)out_size; (void)ws_size;
  const float* x = (const float*)d_in[0];
  const float* Wq = (const float*)d_in[1];
  const float* bq = (const float*)d_in[2];
  const float* Wk = (const float*)d_in[3];
  const float* bk = (const float*)d_in[4];
  const float* Wv = (const float*)d_in[5];
  const float* bv = (const float*)d_in[6];
  const float* rel_h = (const float*)d_in[7];
  const float* rel_w = (const float*)d_in[8];
  float* out = (float*)d_out;

  char* ws = (char*)d_ws;
  _Float16* Xt   = (_Float16*)(ws);                          // 16 MiB
  _Float16* Wall = (_Float16*)(ws + (16u << 20));            // 1.5 MiB
  _Float16* post = (_Float16*)(ws + (18u << 20));            // 1 MiB
  _Float16* Kext = (_Float16*)(ws + (19u << 20));            // 32 MiB
  _Float16* vw   = (_Float16*)(ws + (51u << 20));            // 16 MiB

  hipLaunchKernelGGL(prep_kernel, dim3(5120), dim3(256), 0, stream,
                     Wq, Wk, Wv, rel_h, rel_w, Wall, post);
  hipLaunchKernelGGL(transpose_kernel, dim3(2048), dim3(256), 0, stream, x, Xt);
  hipLaunchKernelGGL(qkv_gemm, dim3(1536), dim3(256), 0, stream,
                     Wall, Xt, bq, bk, bv, Kext, vw);
  hipLaunchKernelGGL(attn_kernel, dim3(4096), dim3(64), 0, stream,
                     Kext, vw, post, x, out);
}

// Round 5
// 188.723 us; speedup vs baseline: 1.3734x; 1.3734x over previous
//
#include <hip/hip_runtime.h>
#include <hip/hip_bf16.h>

typedef _Float16 f16x8 __attribute__((ext_vector_type(8)));
typedef float f32x4 __attribute__((ext_vector_type(4)));
typedef float f32x16 __attribute__((ext_vector_type(16)));
typedef unsigned int u32;
typedef u32 u32x4 __attribute__((ext_vector_type(4)));

#define LOG2E 1.4426950408889634f

// B=16, C=512, HEAD=8, D=64, N=1024 (W=H=32)

__device__ inline void gll16(const void* g, void* l) {
  __builtin_amdgcn_global_load_lds(
      (const __attribute__((address_space(1))) void*)g,
      (__attribute__((address_space(3))) void*)l, 16, 0, 0);
}

// ---------------- prep: Wall f16 + pos f16 (pos pre-scaled by log2e) ----------------
__global__ __launch_bounds__(256) void prep_kernel(
    const float* __restrict__ Wq, const float* __restrict__ Wk, const float* __restrict__ Wv,
    const float* __restrict__ rel_h, const float* __restrict__ rel_w,
    _Float16* __restrict__ Wall, _Float16* __restrict__ post) {
  int idx = blockIdx.x * 256 + threadIdx.x;
  if (idx < 1536 * 512) {
    int o = idx >> 9;
    float wv;
    if (o < 512) wv = Wq[idx];
    else if (o < 1024) wv = Wk[idx - 512 * 512];
    else wv = Wv[idx - 1024 * 512];
    Wall[idx] = (_Float16)wv;
  } else {
    int p = idx - 1536 * 512;            // [0, 8*1024*64)
    int h = p >> 16;
    int rem = p & 65535;
    int n = rem >> 6;
    int d = rem & 63;
    float v = rel_h[(h * 64 + d) * 32 + (n & 31)] + rel_w[(h * 64 + d) * 32 + (n >> 5)];
    post[p] = (_Float16)(v * LOG2E);
  }
}

// ---------------- transpose: x[B,C,N] f32 -> Xt[B*N, C] f16 ----------------
__global__ __launch_bounds__(256) void transpose_kernel(
    const float* __restrict__ x, _Float16* __restrict__ Xt) {
  __shared__ float tl[64][65];
  int bid = blockIdx.x;
  int b = bid >> 7;
  int rem = bid & 127;
  int c0 = (rem >> 4) * 64;
  int n0 = (rem & 15) * 64;
  int t = threadIdx.x;
#pragma unroll
  for (int p = 0; p < 16; ++p) {
    int idx = p * 256 + t;
    int i = idx >> 6, j = idx & 63;
    tl[i][j] = x[((size_t)b * 512 + c0 + i) * 1024 + n0 + j];
  }
  __syncthreads();
#pragma unroll
  for (int p = 0; p < 16; ++p) {
    int idx = p * 256 + t;
    int j = idx >> 6, i = idx & 63;
    Xt[((size_t)b * 1024 + n0 + j) * 512 + c0 + i] = (_Float16)tl[i][j];
  }
}

// ---------------- QKV projection GEMM ----------------
// writes Kext[b][h][n][0:64]=k*log2e, [64:128]=q ; v[b][h][d][n]  (f16)
__global__ __launch_bounds__(256) void qkv_gemm(
    const _Float16* __restrict__ Wall, const _Float16* __restrict__ Xt,
    const float* __restrict__ bq, const float* __restrict__ bk, const float* __restrict__ bv,
    _Float16* __restrict__ kext, _Float16* __restrict__ vv) {
  __shared__ _Float16 At[128 * 64];
  __shared__ _Float16 Bt[128 * 64];
  int bid = blockIdx.x;
  int mb = bid >> 7, nb = bid & 127;
  int o0 = mb * 128, j0 = nb * 128;
  int t = threadIdx.x;
  int w = t >> 6, l = t & 63, lg = l >> 4, lc = l & 15;
  int wm = w >> 1, wn = w & 1;
  f32x4 acc[4][4];
#pragma unroll
  for (int a = 0; a < 4; ++a)
#pragma unroll
    for (int bb = 0; bb < 4; ++bb) acc[a][bb] = (f32x4){0.f, 0.f, 0.f, 0.f};

  for (int k0 = 0; k0 < 512; k0 += 64) {
    __syncthreads();
#pragma unroll
    for (int p = 0; p < 4; ++p) {
      int li = p * 256 + t;            // 16B chunk index
      int row = li >> 3;               // tile row
      int colb = (li & 7) << 4;        // linear byte col in row
      int scol = (colb ^ ((row & 7) << 4)) >> 1;  // inverse-swizzled f16 col
      gll16(Wall + (size_t)(o0 + row) * 512 + k0 + scol, At + (size_t)li * 8);
      gll16(Xt + (size_t)(j0 + row) * 512 + k0 + scol, Bt + (size_t)li * 8);
    }
    __syncthreads();
#pragma unroll
    for (int kf = 0; kf < 2; ++kf) {
      int kbyte = kf * 64 + lg * 16;
      f16x8 af[4], bf[4];
#pragma unroll
      for (int mi = 0; mi < 4; ++mi) {
        int row = wm * 64 + mi * 16 + lc;
        af[mi] = *(const f16x8*)((const char*)At + row * 128 + (kbyte ^ ((row & 7) << 4)));
      }
#pragma unroll
      for (int ni = 0; ni < 4; ++ni) {
        int row = wn * 64 + ni * 16 + lc;
        bf[ni] = *(const f16x8*)((const char*)Bt + row * 128 + (kbyte ^ ((row & 7) << 4)));
      }
#pragma unroll
      for (int mi = 0; mi < 4; ++mi)
#pragma unroll
        for (int ni = 0; ni < 4; ++ni)
          acc[mi][ni] = __builtin_amdgcn_mfma_f32_16x16x32_f16(af[mi], bf[ni], acc[mi][ni], 0, 0, 0);
    }
  }

  int mode = mb >> 2;  // 0=q, 1=k, 2=v
  const float* bias = (mode == 0) ? bq : ((mode == 1) ? bk : bv);
#pragma unroll
  for (int mi = 0; mi < 4; ++mi) {
    int obase = o0 + wm * 64 + mi * 16 + 4 * lg - mode * 512;
#pragma unroll
    for (int ni = 0; ni < 4; ++ni) {
      int j = j0 + wn * 64 + ni * 16 + lc;
      int b = j >> 10, n = j & 1023;
#pragma unroll
      for (int r = 0; r < 4; ++r) {
        int op = obase + r;                 // channel within matrix [0,512)
        float y = acc[mi][ni][r] + bias[op];
        if (mode == 1) y *= LOG2E;          // fold exp2 base change into k
        int h = op >> 6, d = op & 63;
        if (mode < 2) {
          size_t off = ((((size_t)b * 8 + h) * 1024 + n) * 128) + d + (mode == 0 ? 64 : 0);
          kext[off] = (_Float16)y;
        } else {
          vv[(((size_t)b * 8 + h) * 64 + d) * 1024 + n] = (_Float16)y;
        }
      }
    }
  }
}

// ---------------- fused flash attention + residual (32x32 MFMA, reg-resident P) --------
// S = mfma32(Kext_A, Qext_B): C[m-row][q-col=l&31]; softmax per-lane (16 m vals);
// P redistributed to PV B-frags via cvt_pkrtz + shfl_xor(32) + select; PV:
// oacc = mfma32(V_A, P_B) -> C[d-row][q-col]. One barrier per 64-m tile.
__global__ __launch_bounds__(256) void attn_kernel(
    const _Float16* __restrict__ kext, const _Float16* __restrict__ vv,
    const _Float16* __restrict__ post,
    const float* __restrict__ x, float* __restrict__ out) {
  __shared__ _Float16 Ke[2][8192];   // 64 rows x 256B, 16B-chunk rotation (c+row)&15
  int bid = blockIdx.x;
  int bh = bid & 127, qb = bid >> 7;   // same-bh blocks share XCD
  int b = bh >> 3, h = bh & 7;
  int t = threadIdx.x, w = t >> 6, l = t & 63;
  int lw = l & 31, hh = l >> 5;        // q-col lane, lane-half
  const _Float16* keg = kext + (size_t)bh * (1024 * 128);
  const _Float16* vbh = vv + (size_t)bh * 65536;
  const _Float16* ph = post + (size_t)h * 65536;
  int q0 = qb * 128 + w * 32;
  int qq = q0 + lw;

  // Q-ext B-frags: B[k = 16*kk + 8*hh + j][q = lw], resident all kernel (32 VGPR)
  f16x8 aq[8];
#pragma unroll
  for (int kk = 0; kk < 8; ++kk) {
    const _Float16* src = (kk < 4)
        ? keg + (size_t)qq * 128 + 64 + kk * 16 + hh * 8
        : ph + (size_t)qq * 64 + (kk - 4) * 16 + hh * 8;
    aq[kk] = *(const f16x8*)src;
  }

  float m_r = -1e30f, l_r = 0.f;
  f32x16 oacc[2];
  oacc[0] = (f32x16)(0.f);
  oacc[1] = (f32x16)(0.f);

  // stage K-tile (64 x 128 f16) into Ke[bufi]; source pre-rotated so LDS
  // phys chunk pc at row holds logical chunk (pc - row) & 15
  auto stage = [&](int bufi, int mt) {
    int m0 = mt << 6;
#pragma unroll
    for (int p = 0; p < 4; ++p) {
      int li = p * 256 + t;
      int row = li >> 4, pc = li & 15;
      int c = (pc - row) & 15;
      gll16(keg + (size_t)(m0 + row) * 128 + c * 8, (char*)Ke[bufi] + li * 16);
    }
  };

  stage(0, 0);
  __syncthreads();
  int buf = 0;

  for (int mt = 0; mt < 16; ++mt) {
    int m0 = mt << 6;
    if (mt + 1 < 16) stage(buf ^ 1, mt + 1);
    const char* keb = (const char*)Ke[buf];

#pragma unroll
    for (int s = 0; s < 2; ++s) {
      int ms0 = m0 + s * 32;
      // V A-frags direct from global (L2-resident), issued early
      f16x8 va[2][2];  // [p][dstrip]
#pragma unroll
      for (int p = 0; p < 2; ++p)
#pragma unroll
        for (int ds = 0; ds < 2; ++ds)
          va[p][ds] = *(const f16x8*)(vbh + (size_t)(ds * 32 + lw) * 1024 + ms0 + p * 16 + 8 * hh);

      // QK^T-ext: A = K rows (m), B = Q cols (q). C[m][q=lw].
      int rt = s * 32 + lw;
      const char* rowp = keb + rt * 256;
      f32x16 sS = (f32x16)(0.f);
      __builtin_amdgcn_s_setprio(1);
#pragma unroll
      for (int kk = 0; kk < 8; ++kk) {
        int pc = (2 * kk + hh + rt) & 15;
        f16x8 kf = *(const f16x8*)(rowp + pc * 16);
        sS = __builtin_amdgcn_mfma_f32_32x32x16_f16(kf, aq[kk], sS, 0, 0, 0);
      }
      __builtin_amdgcn_s_setprio(0);

      // online softmax (log2 domain); lane owns q=lw, 16 m-values (rows r+8g+4hh)
      float mx = sS[0];
#pragma unroll
      for (int i = 1; i < 16; ++i) mx = fmaxf(mx, sS[i]);
      mx = fmaxf(mx, __shfl_xor(mx, 32));
      float mnew = fmaxf(m_r, mx);
      bool nos = (mnew == m_r);
      float scl = exp2f(m_r - mnew);
      float pr[16];
      float rsum = 0.f;
#pragma unroll
      for (int i = 0; i < 16; ++i) { pr[i] = exp2f(sS[i] - mnew); rsum += pr[i]; }
      rsum += __shfl_xor(rsum, 32);
      l_r = l_r * scl + rsum;
      m_r = mnew;
      if (!__all(nos)) {   // exact skip: scl==1 on all lanes when skipped
#pragma unroll
        for (int i = 0; i < 16; ++i) { oacc[0][i] *= scl; oacc[1][i] *= scl; }
      }

      // pack P to f16 pairs: ulo[g] = m(8g+4hh, +1), uhi[g] = m(8g+4hh+2, +3)
      u32 ulo[4], uhi[4];
#pragma unroll
      for (int g = 0; g < 4; ++g) {
        ulo[g] = __builtin_bit_cast(u32, __builtin_amdgcn_cvt_pkrtz(pr[4 * g], pr[4 * g + 1]));
        uhi[g] = __builtin_bit_cast(u32, __builtin_amdgcn_cvt_pkrtz(pr[4 * g + 2], pr[4 * g + 3]));
      }

      // PV: B-frag P[k=16p+8hh+j][q=lw] assembled via cross-half exchange
      __builtin_amdgcn_s_setprio(1);
#pragma unroll
      for (int p = 0; p < 2; ++p) {
        u32 a = ulo[2 * p], bb = ulo[2 * p + 1];
        u32 cc = uhi[2 * p], dd = uhi[2 * p + 1];
        u32 sa = __shfl_xor(a, 32), sb = __shfl_xor(bb, 32);
        u32 sc = __shfl_xor(cc, 32), sd = __shfl_xor(dd, 32);
        u32x4 tv;
        tv.x = hh ? sb : a;    // m-pair 16p+8hh+0,1
        tv.y = hh ? sd : cc;   // +2,3
        tv.z = hh ? bb : sa;   // +4,5
        tv.w = hh ? dd : sc;   // +6,7
        f16x8 pb = __builtin_bit_cast(f16x8, tv);
        oacc[0] = __builtin_amdgcn_mfma_f32_32x32x16_f16(va[p][0], pb, oacc[0], 0, 0, 0);
        oacc[1] = __builtin_amdgcn_mfma_f32_32x32x16_f16(va[p][1], pb, oacc[1], 0, 0, 0);
      }
      __builtin_amdgcn_s_setprio(0);
    }
    __syncthreads();  // all waves done with buf; staged loads for buf^1 drained
    buf ^= 1;
  }

  // epilogue: C row = (reg&3)+8*(reg>>2)+4*hh -> d = 32ds+8g+4hh+rr; q=qq
  float inv = 1.0f / l_r;
#pragma unroll
  for (int ds = 0; ds < 2; ++ds)
#pragma unroll
    for (int g = 0; g < 4; ++g)
#pragma unroll
      for (int rr = 0; rr < 4; ++rr) {
        int d = ds * 32 + g * 8 + 4 * hh + rr;
        size_t off = ((size_t)b * 512 + h * 64 + d) * 1024 + qq;
        out[off] = oacc[ds][g * 4 + rr] * inv + x[off];
      }
}

extern "C" void kernel_launch(void* const* d_in, const int* in_sizes, int n_in,
                              void* d_out, int out_size, void* d_ws, size_t ws_size,
                              hipStream_t stream) {
  (void)in_sizes; (void)n_in; (void)out_size; (void)ws_size;
  const float* x = (const float*)d_in[0];
  const float* Wq = (const float*)d_in[1];
  const float* bq = (const float*)d_in[2];
  const float* Wk = (const float*)d_in[3];
  const float* bk = (const float*)d_in[4];
  const float* Wv = (const float*)d_in[5];
  const float* bv = (const float*)d_in[6];
  const float* rel_h = (const float*)d_in[7];
  const float* rel_w = (const float*)d_in[8];
  float* out = (float*)d_out;

  char* ws = (char*)d_ws;
  _Float16* Xt   = (_Float16*)(ws);                          // 16 MiB
  _Float16* Wall = (_Float16*)(ws + (16u << 20));            // 1.5 MiB
  _Float16* post = (_Float16*)(ws + (18u << 20));            // 1 MiB
  _Float16* Kext = (_Float16*)(ws + (19u << 20));            // 32 MiB
  _Float16* vw   = (_Float16*)(ws + (51u << 20));            // 16 MiB

  hipLaunchKernelGGL(prep_kernel, dim3(5120), dim3(256), 0, stream,
                     Wq, Wk, Wv, rel_h, rel_w, Wall, post);
  hipLaunchKernelGGL(transpose_kernel, dim3(2048), dim3(256), 0, stream, x, Xt);
  hipLaunchKernelGGL(qkv_gemm, dim3(1536), dim3(256), 0, stream,
                     Wall, Xt, bq, bk, bv, Kext, vw);
  hipLaunchKernelGGL(attn_kernel, dim3(1024), dim3(256), 0, stream,
                     Kext, vw, post, x, out);
}

// Round 6
// 184.053 us; speedup vs baseline: 1.4083x; 1.0254x over previous
//
#include <hip/hip_runtime.h>
#include <hip/hip_bf16.h>

typedef _Float16 f16x8 __attribute__((ext_vector_type(8)));
typedef float f32x4 __attribute__((ext_vector_type(4)));
typedef float f32x16 __attribute__((ext_vector_type(16)));
typedef unsigned int u32;
typedef u32 u32x4 __attribute__((ext_vector_type(4)));

#define LOG2E 1.4426950408889634f

// B=16, C=512, HEAD=8, D=64, N=1024 (W=H=32)

__device__ inline void gll16(const void* g, void* l) {
  __builtin_amdgcn_global_load_lds(
      (const __attribute__((address_space(1))) void*)g,
      (__attribute__((address_space(3))) void*)l, 16, 0, 0);
}

// ---------------- prep: Wall f16 + pos f16 (pos pre-scaled by log2e) ----------------
__global__ __launch_bounds__(256) void prep_kernel(
    const float* __restrict__ Wq, const float* __restrict__ Wk, const float* __restrict__ Wv,
    const float* __restrict__ rel_h, const float* __restrict__ rel_w,
    _Float16* __restrict__ Wall, _Float16* __restrict__ post) {
  int idx = blockIdx.x * 256 + threadIdx.x;
  if (idx < 1536 * 512) {
    int o = idx >> 9;
    float wv;
    if (o < 512) wv = Wq[idx];
    else if (o < 1024) wv = Wk[idx - 512 * 512];
    else wv = Wv[idx - 1024 * 512];
    Wall[idx] = (_Float16)wv;
  } else {
    int p = idx - 1536 * 512;            // [0, 8*1024*64)
    int h = p >> 16;
    int rem = p & 65535;
    int n = rem >> 6;
    int d = rem & 63;
    float v = rel_h[(h * 64 + d) * 32 + (n & 31)] + rel_w[(h * 64 + d) * 32 + (n >> 5)];
    post[p] = (_Float16)(v * LOG2E);
  }
}

// ---------------- transpose: x[B,C,N] f32 -> Xt[B*N, C] f16 ----------------
__global__ __launch_bounds__(256) void transpose_kernel(
    const float* __restrict__ x, _Float16* __restrict__ Xt) {
  __shared__ float tl[64][65];
  int bid = blockIdx.x;
  int b = bid >> 7;
  int rem = bid & 127;
  int c0 = (rem >> 4) * 64;
  int n0 = (rem & 15) * 64;
  int t = threadIdx.x;
#pragma unroll
  for (int p = 0; p < 16; ++p) {
    int idx = p * 256 + t;
    int i = idx >> 6, j = idx & 63;
    tl[i][j] = x[((size_t)b * 512 + c0 + i) * 1024 + n0 + j];
  }
  __syncthreads();
#pragma unroll
  for (int p = 0; p < 16; ++p) {
    int idx = p * 256 + t;
    int j = idx >> 6, i = idx & 63;
    Xt[((size_t)b * 1024 + n0 + j) * 512 + c0 + i] = (_Float16)tl[i][j];
  }
}

// ---------------- QKV projection GEMM ----------------
// writes Kext[b][h][n][0:64]=k*log2e, [64:128]=q ; v[b][h][d][n]  (f16)
__global__ __launch_bounds__(256) void qkv_gemm(
    const _Float16* __restrict__ Wall, const _Float16* __restrict__ Xt,
    const float* __restrict__ bq, const float* __restrict__ bk, const float* __restrict__ bv,
    _Float16* __restrict__ kext, _Float16* __restrict__ vv) {
  __shared__ _Float16 At[128 * 64];
  __shared__ _Float16 Bt[128 * 64];
  int bid = blockIdx.x;
  int mb = bid >> 7, nb = bid & 127;
  int o0 = mb * 128, j0 = nb * 128;
  int t = threadIdx.x;
  int w = t >> 6, l = t & 63, lg = l >> 4, lc = l & 15;
  int wm = w >> 1, wn = w & 1;
  f32x4 acc[4][4];
#pragma unroll
  for (int a = 0; a < 4; ++a)
#pragma unroll
    for (int bb = 0; bb < 4; ++bb) acc[a][bb] = (f32x4){0.f, 0.f, 0.f, 0.f};

  for (int k0 = 0; k0 < 512; k0 += 64) {
    __syncthreads();
#pragma unroll
    for (int p = 0; p < 4; ++p) {
      int li = p * 256 + t;            // 16B chunk index
      int row = li >> 3;               // tile row
      int colb = (li & 7) << 4;        // linear byte col in row
      int scol = (colb ^ ((row & 7) << 4)) >> 1;  // inverse-swizzled f16 col
      gll16(Wall + (size_t)(o0 + row) * 512 + k0 + scol, At + (size_t)li * 8);
      gll16(Xt + (size_t)(j0 + row) * 512 + k0 + scol, Bt + (size_t)li * 8);
    }
    __syncthreads();
#pragma unroll
    for (int kf = 0; kf < 2; ++kf) {
      int kbyte = kf * 64 + lg * 16;
      f16x8 af[4], bf[4];
#pragma unroll
      for (int mi = 0; mi < 4; ++mi) {
        int row = wm * 64 + mi * 16 + lc;
        af[mi] = *(const f16x8*)((const char*)At + row * 128 + (kbyte ^ ((row & 7) << 4)));
      }
#pragma unroll
      for (int ni = 0; ni < 4; ++ni) {
        int row = wn * 64 + ni * 16 + lc;
        bf[ni] = *(const f16x8*)((const char*)Bt + row * 128 + (kbyte ^ ((row & 7) << 4)));
      }
#pragma unroll
      for (int mi = 0; mi < 4; ++mi)
#pragma unroll
        for (int ni = 0; ni < 4; ++ni)
          acc[mi][ni] = __builtin_amdgcn_mfma_f32_16x16x32_f16(af[mi], bf[ni], acc[mi][ni], 0, 0, 0);
    }
  }

  int mode = mb >> 2;  // 0=q, 1=k, 2=v
  const float* bias = (mode == 0) ? bq : ((mode == 1) ? bk : bv);
#pragma unroll
  for (int mi = 0; mi < 4; ++mi) {
    int obase = o0 + wm * 64 + mi * 16 + 4 * lg - mode * 512;
#pragma unroll
    for (int ni = 0; ni < 4; ++ni) {
      int j = j0 + wn * 64 + ni * 16 + lc;
      int b = j >> 10, n = j & 1023;
#pragma unroll
      for (int r = 0; r < 4; ++r) {
        int op = obase + r;                 // channel within matrix [0,512)
        float y = acc[mi][ni][r] + bias[op];
        if (mode == 1) y *= LOG2E;          // fold exp2 base change into k
        int h = op >> 6, d = op & 63;
        if (mode < 2) {
          size_t off = ((((size_t)b * 8 + h) * 1024 + n) * 128) + d + (mode == 0 ? 64 : 0);
          kext[off] = (_Float16)y;
        } else {
          vv[(((size_t)b * 8 + h) * 64 + d) * 1024 + n] = (_Float16)y;
        }
      }
    }
  }
}

// ---------------- fused flash attention + residual (32x32 MFMA, reg-resident P) --------
__global__ __launch_bounds__(256, 4) void attn_kernel(
    const _Float16* __restrict__ kext, const _Float16* __restrict__ vv,
    const _Float16* __restrict__ post,
    const float* __restrict__ x, float* __restrict__ out) {
  __shared__ _Float16 Ke[2][8192];   // 64 rows x 256B, 16B-chunk rotation (c+row)&15
  int bid = blockIdx.x;
  int bh = bid & 127, qb = bid >> 7;   // same-bh blocks share XCD
  int b = bh >> 3, h = bh & 7;
  int t = threadIdx.x, l = t & 63;
  int lw = l & 31, hh = l >> 5;        // q-col lane, lane-half
  const _Float16* keg = kext + (size_t)bh * (1024 * 128);
  const _Float16* vbh = vv + (size_t)bh * 65536;
  const _Float16* ph = post + (size_t)h * 65536;
  int q0 = qb * 128 + (t >> 6) * 32;
  int qq = q0 + lw;

  // Q-ext B-frags: B[k = 16*kk + 8*hh + j][q = lw], resident all kernel (32 VGPR)
  f16x8 aq[8];
#pragma unroll
  for (int kk = 0; kk < 8; ++kk) {
    const _Float16* src = (kk < 4)
        ? keg + (size_t)qq * 128 + 64 + kk * 16 + hh * 8
        : ph + (size_t)qq * 64 + (kk - 4) * 16 + hh * 8;
    aq[kk] = *(const f16x8*)src;
  }

  // precomputed K ds-read byte offsets (s=0, buf=0); s adds 8192, buf adds 16384 (imm)
  u32 dsoff[8];
#pragma unroll
  for (int kk = 0; kk < 8; ++kk)
    dsoff[kk] = (u32)(lw * 256 + (((2 * kk + hh + lw) & 15) << 4));

  // V base pointers (d-strip 0/1)
  const _Float16* vb0 = vbh + (size_t)lw * 1024 + 8 * hh;
  const _Float16* vb1 = vb0 + 32 * 1024;

  float m_r = -1e30f, l_r = 0.f;
  f32x16 oacc[2];
  oacc[0] = (f32x16)(0.f);
  oacc[1] = (f32x16)(0.f);

  // per-lane staging offsets: li = p*256 + t
  int srow = t >> 4, spc = t & 15;

  auto stage = [&](int bufi, int mt) {
    int m0 = mt << 6;
#pragma unroll
    for (int p = 0; p < 4; ++p) {
      int row = p * 16 + srow;
      int c = (spc - row) & 15;
      gll16(keg + (size_t)(m0 + row) * 128 + c * 8,
            (char*)Ke[bufi] + (size_t)(p * 256 + t) * 16);
    }
  };

  auto compute = [&](const char* kbase, int mt) {
    int m0 = mt << 6;
#pragma unroll
    for (int s = 0; s < 2; ++s) {
      int ms0 = m0 + s * 32;
      // V A-frags direct from global (L2-resident), issued early
      f16x8 va[2][2];
#pragma unroll
      for (int p = 0; p < 2; ++p) {
        va[p][0] = *(const f16x8*)(vb0 + ms0 + p * 16);
        va[p][1] = *(const f16x8*)(vb1 + ms0 + p * 16);
      }
      // QK^T-ext: C[m-row][q=lw]; ds addrs precomputed, s via +8192 imm
      f32x16 sS = (f32x16)(0.f);
      __builtin_amdgcn_s_setprio(1);
#pragma unroll
      for (int kk = 0; kk < 8; ++kk) {
        f16x8 kf = *(const f16x8*)(kbase + s * 8192 + dsoff[kk]);
        sS = __builtin_amdgcn_mfma_f32_32x32x16_f16(kf, aq[kk], sS, 0, 0, 0);
      }
      __builtin_amdgcn_s_setprio(0);

      // online softmax (log2 domain), defer-rescale THR=8
      float t0 = fmaxf(fmaxf(sS[0], sS[1]), sS[2]);
      float t1 = fmaxf(fmaxf(sS[3], sS[4]), sS[5]);
      float t2 = fmaxf(fmaxf(sS[6], sS[7]), sS[8]);
      float t3 = fmaxf(fmaxf(sS[9], sS[10]), sS[11]);
      float t4 = fmaxf(fmaxf(sS[12], sS[13]), sS[14]);
      float u0 = fmaxf(fmaxf(t0, t1), t2);
      float u1 = fmaxf(fmaxf(t3, t4), sS[15]);
      float mx = fmaxf(u0, u1);
      mx = fmaxf(mx, __shfl_xor(mx, 32));
      if (!__all(mx - m_r <= 8.0f)) {
        float mnew = fmaxf(m_r, mx);
        float scl = exp2f(m_r - mnew);
        l_r *= scl;
#pragma unroll
        for (int i = 0; i < 16; ++i) { oacc[0][i] *= scl; oacc[1][i] *= scl; }
        m_r = mnew;
      }
      // P = exp2(sS - m_r), in place
#pragma unroll
      for (int i = 0; i < 16; ++i) sS[i] = exp2f(sS[i] - m_r);
      // balanced row-sum
      float a0 = sS[0] + sS[1], a1 = sS[2] + sS[3], a2 = sS[4] + sS[5], a3 = sS[6] + sS[7];
      float a4 = sS[8] + sS[9], a5 = sS[10] + sS[11], a6 = sS[12] + sS[13], a7 = sS[14] + sS[15];
      float b0 = a0 + a1, b1 = a2 + a3, b2 = a4 + a5, b3 = a6 + a7;
      float rs = (b0 + b1) + (b2 + b3);
      rs += __shfl_xor(rs, 32);
      l_r += rs;

      // pack P pairs
      u32 ulo[4], uhi[4];
#pragma unroll
      for (int g = 0; g < 4; ++g) {
        ulo[g] = __builtin_bit_cast(u32, __builtin_amdgcn_cvt_pkrtz(sS[4 * g], sS[4 * g + 1]));
        uhi[g] = __builtin_bit_cast(u32, __builtin_amdgcn_cvt_pkrtz(sS[4 * g + 2], sS[4 * g + 3]));
      }

      // PV: assemble B-frag via permlane32_swap (vdst'={lo,src.lo}, vsrc'={dst.hi,hi})
      __builtin_amdgcn_s_setprio(1);
#pragma unroll
      for (int p = 0; p < 2; ++p) {
        u32 A0 = ulo[2 * p], A1 = ulo[2 * p + 1];
        u32 B0 = uhi[2 * p], B1 = uhi[2 * p + 1];
        asm("v_permlane32_swap_b32 %0, %1" : "+v"(A0), "+v"(A1));
        asm("v_permlane32_swap_b32 %0, %1" : "+v"(B0), "+v"(B1));
        u32x4 tv = (u32x4){A0, B0, A1, B1};
        f16x8 pb = __builtin_bit_cast(f16x8, tv);
        oacc[0] = __builtin_amdgcn_mfma_f32_32x32x16_f16(va[p][0], pb, oacc[0], 0, 0, 0);
        oacc[1] = __builtin_amdgcn_mfma_f32_32x32x16_f16(va[p][1], pb, oacc[1], 0, 0, 0);
      }
      __builtin_amdgcn_s_setprio(0);
    }
  };

  stage(0, 0);
  __syncthreads();
  for (int mt2 = 0; mt2 < 16; mt2 += 2) {
    stage(1, mt2 + 1);
    compute((const char*)Ke[0], mt2);
    __syncthreads();
    if (mt2 + 2 < 16) stage(0, mt2 + 2);
    compute((const char*)Ke[1], mt2 + 1);
    __syncthreads();
  }

  // epilogue: C row = (reg&3)+8*(reg>>2)+4*hh -> d = 32ds+8g+4hh+rr; q=qq
  float inv = 1.0f / l_r;
#pragma unroll
  for (int ds = 0; ds < 2; ++ds)
#pragma unroll
    for (int g = 0; g < 4; ++g)
#pragma unroll
      for (int rr = 0; rr < 4; ++rr) {
        int d = ds * 32 + g * 8 + 4 * hh + rr;
        size_t off = ((size_t)b * 512 + h * 64 + d) * 1024 + qq;
        out[off] = oacc[ds][g * 4 + rr] * inv + x[off];
      }
}

extern "C" void kernel_launch(void* const* d_in, const int* in_sizes, int n_in,
                              void* d_out, int out_size, void* d_ws, size_t ws_size,
                              hipStream_t stream) {
  (void)in_sizes; (void)n_in; (void)out_size; (void)ws_size;
  const float* x = (const float*)d_in[0];
  const float* Wq = (const float*)d_in[1];
  const float* bq = (const float*)d_in[2];
  const float* Wk = (const float*)d_in[3];
  const float* bk = (const float*)d_in[4];
  const float* Wv = (const float*)d_in[5];
  const float* bv = (const float*)d_in[6];
  const float* rel_h = (const float*)d_in[7];
  const float* rel_w = (const float*)d_in[8];
  float* out = (float*)d_out;

  char* ws = (char*)d_ws;
  _Float16* Xt   = (_Float16*)(ws);                          // 16 MiB
  _Float16* Wall = (_Float16*)(ws + (16u << 20));            // 1.5 MiB
  _Float16* post = (_Float16*)(ws + (18u << 20));            // 1 MiB
  _Float16* Kext = (_Float16*)(ws + (19u << 20));            // 32 MiB
  _Float16* vw   = (_Float16*)(ws + (51u << 20));            // 16 MiB

  hipLaunchKernelGGL(prep_kernel, dim3(5120), dim3(256), 0, stream,
                     Wq, Wk, Wv, rel_h, rel_w, Wall, post);
  hipLaunchKernelGGL(transpose_kernel, dim3(2048), dim3(256), 0, stream, x, Xt);
  hipLaunchKernelGGL(qkv_gemm, dim3(1536), dim3(256), 0, stream,
                     Wall, Xt, bq, bk, bv, Kext, vw);
  hipLaunchKernelGGL(attn_kernel, dim3(1024), dim3(256), 0, stream,
                     Kext, vw, post, x, out);
}

// Round 7
// 179.439 us; speedup vs baseline: 1.4445x; 1.0257x over previous
//
#include <hip/hip_runtime.h>
#include <hip/hip_bf16.h>

typedef _Float16 f16x8 __attribute__((ext_vector_type(8)));
typedef float f32x4 __attribute__((ext_vector_type(4)));
typedef float f32x16 __attribute__((ext_vector_type(16)));
typedef unsigned int u32;
typedef u32 u32x4 __attribute__((ext_vector_type(4)));

#define LOG2E 1.4426950408889634f

#if __has_builtin(__builtin_amdgcn_exp2f)
#define EXP2(x) __builtin_amdgcn_exp2f(x)
#else
__device__ inline float EXP2(float x) { float r; asm("v_exp_f32 %0, %1\n\ts_nop 0" : "=v"(r) : "v"(x)); return r; }
#endif

// B=16, C=512, HEAD=8, D=64, N=1024 (W=H=32)

__device__ inline void gll16(const void* g, void* l) {
  __builtin_amdgcn_global_load_lds(
      (const __attribute__((address_space(1))) void*)g,
      (__attribute__((address_space(3))) void*)l, 16, 0, 0);
}

// ---------------- prep: Wall f16 + pos f16 (pos pre-scaled by log2e) ----------------
__global__ __launch_bounds__(256) void prep_kernel(
    const float* __restrict__ Wq, const float* __restrict__ Wk, const float* __restrict__ Wv,
    const float* __restrict__ rel_h, const float* __restrict__ rel_w,
    _Float16* __restrict__ Wall, _Float16* __restrict__ post) {
  int idx = blockIdx.x * 256 + threadIdx.x;
  if (idx < 1536 * 512) {
    int o = idx >> 9;
    float wv;
    if (o < 512) wv = Wq[idx];
    else if (o < 1024) wv = Wk[idx - 512 * 512];
    else wv = Wv[idx - 1024 * 512];
    Wall[idx] = (_Float16)wv;
  } else {
    int p = idx - 1536 * 512;            // [0, 8*1024*64)
    int h = p >> 16;
    int rem = p & 65535;
    int n = rem >> 6;
    int d = rem & 63;
    float v = rel_h[(h * 64 + d) * 32 + (n & 31)] + rel_w[(h * 64 + d) * 32 + (n >> 5)];
    post[p] = (_Float16)(v * LOG2E);
  }
}

// ---------------- transpose: x[B,C,N] f32 -> Xt[B*N, C] f16 ----------------
__global__ __launch_bounds__(256) void transpose_kernel(
    const float* __restrict__ x, _Float16* __restrict__ Xt) {
  __shared__ float tl[64][65];
  int bid = blockIdx.x;
  int b = bid >> 7;
  int rem = bid & 127;
  int c0 = (rem >> 4) * 64;
  int n0 = (rem & 15) * 64;
  int t = threadIdx.x;
#pragma unroll
  for (int p = 0; p < 16; ++p) {
    int idx = p * 256 + t;
    int i = idx >> 6, j = idx & 63;
    tl[i][j] = x[((size_t)b * 512 + c0 + i) * 1024 + n0 + j];
  }
  __syncthreads();
#pragma unroll
  for (int p = 0; p < 16; ++p) {
    int idx = p * 256 + t;
    int j = idx >> 6, i = idx & 63;
    Xt[((size_t)b * 1024 + n0 + j) * 512 + c0 + i] = (_Float16)tl[i][j];
  }
}

// ---------------- QKV projection GEMM ----------------
// writes Kext[b][h][n][0:64]=k*log2e, [64:128]=q ; v[b][h][d][n]  (f16)
__global__ __launch_bounds__(256) void qkv_gemm(
    const _Float16* __restrict__ Wall, const _Float16* __restrict__ Xt,
    const float* __restrict__ bq, const float* __restrict__ bk, const float* __restrict__ bv,
    _Float16* __restrict__ kext, _Float16* __restrict__ vv) {
  __shared__ _Float16 At[128 * 64];
  __shared__ _Float16 Bt[128 * 64];
  int bid = blockIdx.x;
  int mb = bid >> 7, nb = bid & 127;
  int o0 = mb * 128, j0 = nb * 128;
  int t = threadIdx.x;
  int w = t >> 6, l = t & 63, lg = l >> 4, lc = l & 15;
  int wm = w >> 1, wn = w & 1;
  f32x4 acc[4][4];
#pragma unroll
  for (int a = 0; a < 4; ++a)
#pragma unroll
    for (int bb = 0; bb < 4; ++bb) acc[a][bb] = (f32x4){0.f, 0.f, 0.f, 0.f};

  for (int k0 = 0; k0 < 512; k0 += 64) {
    __syncthreads();
#pragma unroll
    for (int p = 0; p < 4; ++p) {
      int li = p * 256 + t;            // 16B chunk index
      int row = li >> 3;               // tile row
      int colb = (li & 7) << 4;        // linear byte col in row
      int scol = (colb ^ ((row & 7) << 4)) >> 1;  // inverse-swizzled f16 col
      gll16(Wall + (size_t)(o0 + row) * 512 + k0 + scol, At + (size_t)li * 8);
      gll16(Xt + (size_t)(j0 + row) * 512 + k0 + scol, Bt + (size_t)li * 8);
    }
    __syncthreads();
#pragma unroll
    for (int kf = 0; kf < 2; ++kf) {
      int kbyte = kf * 64 + lg * 16;
      f16x8 af[4], bf[4];
#pragma unroll
      for (int mi = 0; mi < 4; ++mi) {
        int row = wm * 64 + mi * 16 + lc;
        af[mi] = *(const f16x8*)((const char*)At + row * 128 + (kbyte ^ ((row & 7) << 4)));
      }
#pragma unroll
      for (int ni = 0; ni < 4; ++ni) {
        int row = wn * 64 + ni * 16 + lc;
        bf[ni] = *(const f16x8*)((const char*)Bt + row * 128 + (kbyte ^ ((row & 7) << 4)));
      }
#pragma unroll
      for (int mi = 0; mi < 4; ++mi)
#pragma unroll
        for (int ni = 0; ni < 4; ++ni)
          acc[mi][ni] = __builtin_amdgcn_mfma_f32_16x16x32_f16(af[mi], bf[ni], acc[mi][ni], 0, 0, 0);
    }
  }

  int mode = mb >> 2;  // 0=q, 1=k, 2=v
  const float* bias = (mode == 0) ? bq : ((mode == 1) ? bk : bv);
#pragma unroll
  for (int mi = 0; mi < 4; ++mi) {
    int obase = o0 + wm * 64 + mi * 16 + 4 * lg - mode * 512;
#pragma unroll
    for (int ni = 0; ni < 4; ++ni) {
      int j = j0 + wn * 64 + ni * 16 + lc;
      int b = j >> 10, n = j & 1023;
#pragma unroll
      for (int r = 0; r < 4; ++r) {
        int op = obase + r;                 // channel within matrix [0,512)
        float y = acc[mi][ni][r] + bias[op];
        if (mode == 1) y *= LOG2E;          // fold exp2 base change into k
        int h = op >> 6, d = op & 63;
        if (mode < 2) {
          size_t off = ((((size_t)b * 8 + h) * 1024 + n) * 128) + d + (mode == 0 ? 64 : 0);
          kext[off] = (_Float16)y;
        } else {
          vv[(((size_t)b * 8 + h) * 64 + d) * 1024 + n] = (_Float16)y;
        }
      }
    }
  }
}

// ---------------- fused flash attention + residual (32x32 MFMA, reg-resident P) --------
__global__ __launch_bounds__(256) void attn_kernel(
    const _Float16* __restrict__ kext, const _Float16* __restrict__ vv,
    const _Float16* __restrict__ post,
    const float* __restrict__ x, float* __restrict__ out) {
  __shared__ _Float16 Ke[2][8192];   // 64 rows x 256B, 16B-chunk rotation (c+row)&15
  int bid = blockIdx.x;
  int bh = bid & 127, qb = bid >> 7;   // same-bh blocks share XCD
  int b = bh >> 3, h = bh & 7;
  int t = threadIdx.x, l = t & 63;
  int lw = l & 31, hh = l >> 5;        // q-col lane, lane-half
  const _Float16* keg = kext + (size_t)bh * (1024 * 128);
  const _Float16* vbh = vv + (size_t)bh * 65536;
  const _Float16* ph = post + (size_t)h * 65536;
  int q0 = qb * 128 + (t >> 6) * 32;
  int qq = q0 + lw;

  // Q-ext B-frags: B[k = 16*kk + 8*hh + j][q = lw], resident all kernel (32 VGPR)
  f16x8 aq[8];
#pragma unroll
  for (int kk = 0; kk < 8; ++kk) {
    const _Float16* src = (kk < 4)
        ? keg + (size_t)qq * 128 + 64 + kk * 16 + hh * 8
        : ph + (size_t)qq * 64 + (kk - 4) * 16 + hh * 8;
    aq[kk] = *(const f16x8*)src;
  }

  // precomputed K ds-read byte offsets (s=0, buf=0); s adds 8192, buf adds 16384 (imm)
  u32 dsoff[8];
#pragma unroll
  for (int kk = 0; kk < 8; ++kk)
    dsoff[kk] = (u32)(lw * 256 + (((2 * kk + hh + lw) & 15) << 4));

  // V running pointers (advance 64 elems per tile; imm folds s*64 + p*32 B)
  const _Float16* vb0 = vbh + (size_t)lw * 1024 + 8 * hh;
  const _Float16* vb1 = vb0 + 32 * 1024;

  float m_r = -1e30f, l_r = 0.f;
  f32x16 oacc[2];
  oacc[0] = (f32x16)(0.f);
  oacc[1] = (f32x16)(0.f);

  // per-lane staging offsets: li = p*256 + t
  int srow = t >> 4, spc = t & 15;

  auto stage = [&](int bufi, int mt) {
    int m0 = mt << 6;
#pragma unroll
    for (int p = 0; p < 4; ++p) {
      int row = p * 16 + srow;
      int c = (spc - row) & 15;
      gll16(keg + (size_t)(m0 + row) * 128 + c * 8,
            (char*)Ke[bufi] + (size_t)(p * 256 + t) * 16);
    }
  };

  auto compute = [&](const char* kbase) {
#pragma unroll
    for (int s = 0; s < 2; ++s) {
      // V A-frags direct from global (L2-resident), issued early
      f16x8 va[2][2];
#pragma unroll
      for (int p = 0; p < 2; ++p) {
        va[p][0] = *(const f16x8*)(vb0 + s * 32 + p * 16);
        va[p][1] = *(const f16x8*)(vb1 + s * 32 + p * 16);
      }
      // QK^T-ext: C[m-row][q=lw]; ds addrs precomputed, s via +8192 imm
      f32x16 sS = (f32x16)(0.f);
      __builtin_amdgcn_s_setprio(1);
#pragma unroll
      for (int kk = 0; kk < 8; ++kk) {
        f16x8 kf = *(const f16x8*)(kbase + s * 8192 + dsoff[kk]);
        sS = __builtin_amdgcn_mfma_f32_32x32x16_f16(kf, aq[kk], sS, 0, 0, 0);
      }
      __builtin_amdgcn_s_setprio(0);

      // online softmax (log2 domain), defer-rescale THR=8
      float t0 = fmaxf(fmaxf(sS[0], sS[1]), sS[2]);
      float t1 = fmaxf(fmaxf(sS[3], sS[4]), sS[5]);
      float t2 = fmaxf(fmaxf(sS[6], sS[7]), sS[8]);
      float t3 = fmaxf(fmaxf(sS[9], sS[10]), sS[11]);
      float t4 = fmaxf(fmaxf(sS[12], sS[13]), sS[14]);
      float u0 = fmaxf(fmaxf(t0, t1), t2);
      float u1 = fmaxf(fmaxf(t3, t4), sS[15]);
      float mx = fmaxf(u0, u1);
      mx = fmaxf(mx, __shfl_xor(mx, 32));
      if (!__all(mx - m_r <= 8.0f)) {
        float mnew = fmaxf(m_r, mx);
        float scl = EXP2(m_r - mnew);
        l_r *= scl;
#pragma unroll
        for (int i = 0; i < 16; ++i) { oacc[0][i] *= scl; oacc[1][i] *= scl; }
        m_r = mnew;
      }
      // P = exp2(sS - m_r), in place (raw v_exp_f32)
#pragma unroll
      for (int i = 0; i < 16; ++i) sS[i] = EXP2(sS[i] - m_r);
      // balanced row-sum
      float a0 = sS[0] + sS[1], a1 = sS[2] + sS[3], a2 = sS[4] + sS[5], a3 = sS[6] + sS[7];
      float a4 = sS[8] + sS[9], a5 = sS[10] + sS[11], a6 = sS[12] + sS[13], a7 = sS[14] + sS[15];
      float b0 = a0 + a1, b1 = a2 + a3, b2 = a4 + a5, b3 = a6 + a7;
      float rs = (b0 + b1) + (b2 + b3);
      rs += __shfl_xor(rs, 32);
      l_r += rs;

      // pack P pairs
      u32 ulo[4], uhi[4];
#pragma unroll
      for (int g = 0; g < 4; ++g) {
        ulo[g] = __builtin_bit_cast(u32, __builtin_amdgcn_cvt_pkrtz(sS[4 * g], sS[4 * g + 1]));
        uhi[g] = __builtin_bit_cast(u32, __builtin_amdgcn_cvt_pkrtz(sS[4 * g + 2], sS[4 * g + 3]));
      }

      // PV: assemble B-frag via permlane32_swap (vdst'={lo,src.lo}, vsrc'={dst.hi,hi})
      __builtin_amdgcn_s_setprio(1);
#pragma unroll
      for (int p = 0; p < 2; ++p) {
        u32 A0 = ulo[2 * p], A1 = ulo[2 * p + 1];
        u32 B0 = uhi[2 * p], B1 = uhi[2 * p + 1];
        asm("v_permlane32_swap_b32 %0, %1" : "+v"(A0), "+v"(A1));
        asm("v_permlane32_swap_b32 %0, %1" : "+v"(B0), "+v"(B1));
        u32x4 tv = (u32x4){A0, B0, A1, B1};
        f16x8 pb = __builtin_bit_cast(f16x8, tv);
        oacc[0] = __builtin_amdgcn_mfma_f32_32x32x16_f16(va[p][0], pb, oacc[0], 0, 0, 0);
        oacc[1] = __builtin_amdgcn_mfma_f32_32x32x16_f16(va[p][1], pb, oacc[1], 0, 0, 0);
      }
      __builtin_amdgcn_s_setprio(0);
    }
  };

  stage(0, 0);
  asm volatile("s_waitcnt vmcnt(0)\n\ts_barrier" ::: "memory");
  for (int mt = 0; mt < 16; ++mt) {
    if (mt + 1 < 16) stage((mt + 1) & 1, mt + 1);   // other buffer: safe after barrier
    compute((const char*)Ke[mt & 1]);
    vb0 += 64; vb1 += 64;
    if (mt + 1 < 16)
      asm volatile("s_waitcnt vmcnt(0)\n\ts_barrier" ::: "memory");  // own stage landed + all waves done with buf
  }

  // epilogue: C row = (reg&3)+8*(reg>>2)+4*hh -> d = 32ds+8g+4hh+rr; q=qq
  float inv = 1.0f / l_r;
#pragma unroll
  for (int ds = 0; ds < 2; ++ds)
#pragma unroll
    for (int g = 0; g < 4; ++g)
#pragma unroll
      for (int rr = 0; rr < 4; ++rr) {
        int d = ds * 32 + g * 8 + 4 * hh + rr;
        size_t off = ((size_t)b * 512 + h * 64 + d) * 1024 + qq;
        out[off] = oacc[ds][g * 4 + rr] * inv + x[off];
      }
}

extern "C" void kernel_launch(void* const* d_in, const int* in_sizes, int n_in,
                              void* d_out, int out_size, void* d_ws, size_t ws_size,
                              hipStream_t stream) {
  (void)in_sizes; (void)n_in; (void)out_size; (void)ws_size;
  const float* x = (const float*)d_in[0];
  const float* Wq = (const float*)d_in[1];
  const float* bq = (const float*)d_in[2];
  const float* Wk = (const float*)d_in[3];
  const float* bk = (const float*)d_in[4];
  const float* Wv = (const float*)d_in[5];
  const float* bv = (const float*)d_in[6];
  const float* rel_h = (const float*)d_in[7];
  const float* rel_w = (const float*)d_in[8];
  float* out = (float*)d_out;

  char* ws = (char*)d_ws;
  _Float16* Xt   = (_Float16*)(ws);                          // 16 MiB
  _Float16* Wall = (_Float16*)(ws + (16u << 20));            // 1.5 MiB
  _Float16* post = (_Float16*)(ws + (18u << 20));            // 1 MiB
  _Float16* Kext = (_Float16*)(ws + (19u << 20));            // 32 MiB
  _Float16* vw   = (_Float16*)(ws + (51u << 20));            // 16 MiB

  hipLaunchKernelGGL(prep_kernel, dim3(5120), dim3(256), 0, stream,
                     Wq, Wk, Wv, rel_h, rel_w, Wall, post);
  hipLaunchKernelGGL(transpose_kernel, dim3(2048), dim3(256), 0, stream, x, Xt);
  hipLaunchKernelGGL(qkv_gemm, dim3(1536), dim3(256), 0, stream,
                     Wall, Xt, bq, bk, bv, Kext, vw);
  hipLaunchKernelGGL(attn_kernel, dim3(1024), dim3(256), 0, stream,
                     Kext, vw, post, x, out);
}